// Round 2
// baseline (435.587 us; speedup 1.0000x reference)
//
#include <hip/hip_runtime.h>

// CoreSageLayer: x1 = (adj @ x)/deg ; out[k] = [x1|x] @ W[k] + bias, k=0..2
// N=8192, F=256, OUT=256. adj int32 in {0,1} (256 MB = the HBM floor).
//
// R2 restructure vs R1 (433 us):
//  - phase1: grid K-split x4 -> 1024 blocks x 256 thr (4 blocks/CU), M-tile 32,
//    double-buffered LDS adj staging with ONE barrier/step and next-step adj
//    prefetched before the barrier. Partial C (fp32) + partial deg -> ws.
//  - reduce: sums 4 K-split partials, divides by deg, packs bf16 into the
//    phase-2 A-fragment layout.
//  - phase2: 1024 blocks (4/CU) zero-LDS register GEMM M=8192 K=512 N=768.
//  - prep kernels merged into one dispatch.

typedef unsigned short u16;
typedef int   i32x4 __attribute__((ext_vector_type(4)));
typedef unsigned u32x4 __attribute__((ext_vector_type(4)));
typedef float f32x4 __attribute__((ext_vector_type(4)));

__device__ __forceinline__ u16 f2b(float f) {  // fp32 -> bf16 RNE
  unsigned u = __builtin_bit_cast(unsigned, f);
  return (u16)((u + 0x7FFFu + ((u >> 16) & 1u)) >> 16);
}
__device__ __forceinline__ unsigned pack2(float a, float b) {
  return (unsigned)f2b(a) | ((unsigned)f2b(b) << 16);
}
__device__ __forceinline__ f32x4 mfma16(u32x4 a, u32x4 b, f32x4 c) {
  // D = A(16x32)*B(32x16)+C bf16. A/B: lane holds row/col l&15, k=(l>>4)*8+j.
  // C/D: col=l&15, row=(l>>4)*4+reg.
  asm("v_mfma_f32_16x16x32_bf16 %0, %1, %2, %0" : "+v"(c) : "v"(a), "v"(b));
  return c;
}

// ---- prep (one dispatch):
// blocks [0,1024):   xtf  = x bf16, frag-major (k=node, n=feature). 4 MB.
// blocks [1024,2048): nxtf upper half = x bf16 frag-major (k=feat 256..511, m=node).
// blocks [2048,2240): wtf = weight bf16 frag-major (k=feat, n=3*256 cols). 768 KB.
__global__ __launch_bounds__(256) void prep(const float* __restrict__ x,
                                            const float* __restrict__ wgt,
                                            u16* __restrict__ xtf,
                                            u16* __restrict__ nxtf,
                                            u16* __restrict__ wtf) {
  const int b = blockIdx.x, t = threadIdx.x;
  if (b < 1024) {
    int c = b * 256 + t, kc8 = c >> 8, f = c & 255;
    const float* p = x + (size_t)kc8 * 2048 + f;
    u32x4 h;
    h.x = pack2(p[0],    p[256]);  h.y = pack2(p[512],  p[768]);
    h.z = pack2(p[1024], p[1280]); h.w = pack2(p[1536], p[1792]);
    *(u32x4*)(xtf + (size_t)c * 8) = h;
  } else if (b < 2048) {
    int c = (b - 1024) * 256 + t, kc8r = c >> 13, m = c & 8191;
    const float* p = x + (size_t)m * 256 + kc8r * 8;
    f32x4 p0 = *(const f32x4*)p, p1 = *(const f32x4*)(p + 4);
    u32x4 h;
    h.x = pack2(p0.x, p0.y); h.y = pack2(p0.z, p0.w);
    h.z = pack2(p1.x, p1.y); h.w = pack2(p1.z, p1.w);
    *(u32x4*)(nxtf + ((size_t)(32 + kc8r) * 8192 + m) * 8) = h;
  } else {
    int idx = b - 2048, kc8 = idx / 3, c = (idx % 3) * 256 + t;
    int kk = c >> 8, o = c & 255;
    const float* p = wgt + (size_t)kk * 131072 + (size_t)kc8 * 2048 + o;
    u32x4 h;
    h.x = pack2(p[0],    p[256]);  h.y = pack2(p[512],  p[768]);
    h.z = pack2(p[1024], p[1280]); h.w = pack2(p[1536], p[1792]);
    *(u32x4*)(wtf + ((size_t)kc8 * 768 + c) * 8) = h;
  }
}

// ---- phase 1: partial S = adj[m0:m0+32, g*2048:(g+1)*2048] @ x  (bf16 MFMA)
// 1024 blocks x 256 thr: block = (m-tile mt = b>>2, K-split g = b&3).
// 4 waves each own a 64-col N strip and 2 m-frags. Double-buffered LDS adj
// tile (32x64), one barrier/step, adj prefetch one step ahead. deg fused.
__global__ __launch_bounds__(256) void phase1(const int* __restrict__ adj,
                                              const u16* __restrict__ xtf,
                                              float* __restrict__ part,
                                              int* __restrict__ degp) {
  __shared__ __align__(16) u16 As[2][32 * 72];   // [buf][row][64k + 8 pad]
  __shared__ int degs[256];

  const int t = threadIdx.x, l = t & 63, w = t >> 6;
  const int l15 = l & 15, l16 = l >> 4;          // l16 in 0..3
  const int g = blockIdx.x & 3, mt = blockIdx.x >> 2;
  const int m0 = mt * 32, k0g = g * 2048;
  const int r = t >> 3, kq = t & 7;              // staging: row, 8-k quad

  f32x4 acc[2][4] = {};
  int dsum = 0;

  const i32x4* arow = (const i32x4*)(adj + (size_t)(m0 + r) * 8192 + k0g) + kq * 2;
  const int lds_w  = r * 72 + kq * 8;
  const int lds_a0 = l15 * 72 + l16 * 8;
  const int lds_a1 = lds_a0 + 16 * 72;
  const u16* bbase = xtf + ((size_t)(k0g >> 3) + l16) * 2048 + (size_t)(w * 64 + l15) * 8;

  i32x4 p0 = __builtin_nontemporal_load(arow);
  i32x4 p1 = __builtin_nontemporal_load(arow + 1);

  for (int step = 0; step < 32; ++step) {
    dsum += p0.x + p0.y + p0.z + p0.w + p1.x + p1.y + p1.z + p1.w;
    u32x4 h;
    h.x = (p0.x ? 0x3F80u : 0u) | (p0.y ? 0x3F800000u : 0u);
    h.y = (p0.z ? 0x3F80u : 0u) | (p0.w ? 0x3F800000u : 0u);
    h.z = (p1.x ? 0x3F80u : 0u) | (p1.y ? 0x3F800000u : 0u);
    h.w = (p1.z ? 0x3F80u : 0u) | (p1.w ? 0x3F800000u : 0u);
    *(u32x4*)&As[step & 1][lds_w] = h;
    if (step < 31) {   // prefetch next adj tile before the barrier
      p0 = __builtin_nontemporal_load(arow + (step + 1) * 16);
      p1 = __builtin_nontemporal_load(arow + (step + 1) * 16 + 1);
    }
    __syncthreads();
    // safe single barrier: buffer (step+1)&1 was last read at step-1, whose
    // ds_reads retired before that wave reached this barrier.
    const u16* bs = bbase + (size_t)step * 16384;          // 8 kc8-rows/step
    const u16* as_ = &As[step & 1][0];
#pragma unroll
    for (int kc = 0; kc < 2; ++kc) {
      u32x4 a0 = *(const u32x4*)(as_ + lds_a0 + kc * 32);
      u32x4 a1 = *(const u32x4*)(as_ + lds_a1 + kc * 32);
#pragma unroll
      for (int nt = 0; nt < 4; ++nt) {
        u32x4 bfr = *(const u32x4*)(bs + (size_t)kc * 8192 + nt * 128);
        acc[0][nt] = mfma16(a0, bfr, acc[0][nt]);
        acc[1][nt] = mfma16(a1, bfr, acc[1][nt]);
      }
    }
  }
  asm volatile("s_nop 7\n\ts_nop 7\n\ts_nop 7");  // MFMA D -> VALU read hazard

  degs[t] = dsum;
  __syncthreads();
  if (t < 32) {
    int s = 0;
#pragma unroll
    for (int j = 0; j < 8; ++j) s += degs[t * 8 + j];   // threads 8r..8r+7 = row r
    degp[g * 8192 + m0 + t] = s;
  }
  // partial C -> ws (fp32), normal stores (let reduce hit L2/L3)
  float* pc = part + ((size_t)g * 8192 + m0) * 256;
#pragma unroll
  for (int mt2 = 0; mt2 < 2; ++mt2)
#pragma unroll
    for (int nt = 0; nt < 4; ++nt)
#pragma unroll
      for (int i = 0; i < 4; ++i)
        pc[(size_t)(mt2 * 16 + l16 * 4 + i) * 256 + (w * 64 + nt * 16 + l15)] =
            acc[mt2][nt][i];
}

// ---- reduce: x1 = (sum_g part[g]) / deg -> nxtf lower half (bf16 frag-major)
// 1024 blocks x 256: thread = (m, feature-octet kc8). Coalesced partial reads.
__global__ __launch_bounds__(256) void reducek(const float* __restrict__ part,
                                               const int* __restrict__ degp,
                                               u16* __restrict__ nxtf) {
  int c = blockIdx.x * 256 + threadIdx.x;   // 0..262143
  int m = c >> 5, kc8 = c & 31;
  int deg = degp[m] + degp[8192 + m] + degp[16384 + m] + degp[24576 + m];
  float rd = 1.0f / (float)deg;
  const float* p = part + (size_t)m * 256 + kc8 * 8;
  f32x4 s0 = {}, s1 = {};
#pragma unroll
  for (int gg = 0; gg < 4; ++gg) {
    s0 += *(const f32x4*)(p + (size_t)gg * 2097152);
    s1 += *(const f32x4*)(p + (size_t)gg * 2097152 + 4);
  }
  u32x4 h;
  h.x = pack2(s0.x * rd, s0.y * rd); h.y = pack2(s0.z * rd, s0.w * rd);
  h.z = pack2(s1.x * rd, s1.y * rd); h.w = pack2(s1.z * rd, s1.w * rd);
  *(u32x4*)(nxtf + ((size_t)kc8 * 8192 + m) * 8) = h;
}

// ---- phase 2: out[m, c=kk*256+o] = sum_k nx[m][k]*w_tf[c][k] + bias[o]
// M=8192 K=512 N=768. Zero LDS; both operands are ready frags in global.
// Grid (64,16): M-tile 128, N-tile 48; wave w owns rows w*32..w*32+31.
__global__ __launch_bounds__(256) void phase2(const u16* __restrict__ nxtf,
                                              const u16* __restrict__ wtf,
                                              const float* __restrict__ bias,
                                              float* __restrict__ out) {
  const int t = threadIdx.x, l = t & 63, w = t >> 6;
  const int l15 = l & 15, l16 = l >> 4;          // l16 in 0..3
  const int m0 = blockIdx.x * 128, c0 = blockIdx.y * 48;
  f32x4 acc[2][3] = {};
  const u16* abase = nxtf + (size_t)l16 * 65536 + (size_t)(m0 + w * 32 + l15) * 8;
  const u16* bbase = wtf  + (size_t)l16 * 6144  + (size_t)(c0 + l15) * 8;
  float bv[3];
#pragma unroll
  for (int nt = 0; nt < 3; ++nt) bv[nt] = bias[(c0 + nt * 16 + l15) & 255];
#pragma unroll 2
  for (int step = 0; step < 16; ++step) {        // K: 32 per step
    u32x4 a[2], b[3];
    a[0] = *(const u32x4*)(abase + (size_t)step * 262144);
    a[1] = *(const u32x4*)(abase + (size_t)step * 262144 + 128);
#pragma unroll
    for (int nt = 0; nt < 3; ++nt)
      b[nt] = *(const u32x4*)(bbase + (size_t)step * 24576 + nt * 128);
#pragma unroll
    for (int mt2 = 0; mt2 < 2; ++mt2)
#pragma unroll
      for (int nt = 0; nt < 3; ++nt)
        acc[mt2][nt] = mfma16(a[mt2], b[nt], acc[mt2][nt]);
  }
  asm volatile("s_nop 7\n\ts_nop 7\n\ts_nop 7");
#pragma unroll
  for (int mt2 = 0; mt2 < 2; ++mt2)
#pragma unroll
    for (int nt = 0; nt < 3; ++nt) {
      int c = c0 + nt * 16 + l15;
      int kk = c >> 8, o = c & 255;
      float* op = out + (size_t)kk * 2097152 +
                  (size_t)(m0 + w * 32 + mt2 * 16 + l16 * 4) * 256 + o;
#pragma unroll
      for (int i = 0; i < 4; ++i)
        __builtin_nontemporal_store(acc[mt2][nt][i] + bv[nt], op + (size_t)i * 256);
    }
}

extern "C" void kernel_launch(void* const* d_in, const int* in_sizes, int n_in,
                              void* d_out, int out_size, void* d_ws, size_t ws_size,
                              hipStream_t stream) {
  (void)in_sizes; (void)n_in; (void)out_size; (void)ws_size;
  const float* x    = (const float*)d_in[1];
  const int*   adj  = (const int*)d_in[2];
  const float* wgt  = (const float*)d_in[3];
  const float* bias = (const float*)d_in[4];
  float* out = (float*)d_out;

  char* ws = (char*)d_ws;
  u16*   xtf  = (u16*)ws;                       // 4 MB
  u16*   nxtf = (u16*)(ws + (4ull  << 20));     // 8 MB
  u16*   wtf  = (u16*)(ws + (12ull << 20));     // 768 KB (pad to 1 MB)
  float* part = (float*)(ws + (13ull << 20));   // 32 MB (4 x 8192 x 256 f32)
  int*   degp = (int*)(ws + (45ull << 20));     // 128 KB

  prep   <<<2240, 256, 0, stream>>>(x, wgt, xtf, nxtf, wtf);
  phase1 <<<1024, 256, 0, stream>>>(adj, xtf, part, degp);
  reducek<<<1024, 256, 0, stream>>>(part, degp, nxtf);
  phase2 <<<dim3(64, 16), 256, 0, stream>>>(nxtf, wtf, bias, out);
}